// Round 1
// baseline (526.452 us; speedup 1.0000x reference)
//
#include <hip/hip_runtime.h>

#define N_NODES 50000
#define N_EDGES 800000
#define D 64

// One 64-lane wave per edge: lane l scatters feature l of x[src] into agg[dst].
__global__ void __launch_bounds__(256) scatter_add(
    const float* __restrict__ feat,
    const int* __restrict__ src,
    const int* __restrict__ dst,
    float* __restrict__ agg) {
    long long gid = (long long)blockIdx.x * blockDim.x + threadIdx.x;
    int e = (int)(gid >> 6);
    int lane = (int)(gid & 63);
    if (e >= N_EDGES) return;
    int s = src[e];
    int d = dst[e];
    atomicAdd(&agg[(long long)d * D + lane], feat[(long long)s * D + lane]);
}

// out[row] = act( X[row] @ Wr + A[row] @ Wn + b )
// Block = 256 threads = 4 rows x 64 cols. Weights + row tiles staged in LDS.
template<int RELU>
__global__ void __launch_bounds__(256) dual_gemm(
    const float* __restrict__ X, const float* __restrict__ A,
    const float* __restrict__ Wr, const float* __restrict__ Wn,
    const float* __restrict__ bias, float* __restrict__ out) {
    __shared__ float sWr[D][D];   // 16 KB
    __shared__ float sWn[D][D];   // 16 KB
    __shared__ float sX[4][D];    // 1 KB
    __shared__ float sA[4][D];    // 1 KB

    int tid = threadIdx.x;

    // Cooperative load of both 64x64 weight matrices (4096 floats each).
    const float4* Wr4 = (const float4*)Wr;
    const float4* Wn4 = (const float4*)Wn;
    float4* sWr4 = (float4*)&sWr[0][0];
    float4* sWn4 = (float4*)&sWn[0][0];
#pragma unroll
    for (int i = 0; i < 4; i++) {
        sWr4[tid + 256 * i] = Wr4[tid + 256 * i];
        sWn4[tid + 256 * i] = Wn4[tid + 256 * i];
    }

    int rowLocal = tid >> 6;
    int col = tid & 63;
    int row = blockIdx.x * 4 + rowLocal;   // 50000 / 4 = 12500 blocks, exact

    sX[rowLocal][col] = X[(long long)row * D + col];
    sA[rowLocal][col] = A[(long long)row * D + col];
    __syncthreads();

    float acc = bias[col];
#pragma unroll
    for (int k = 0; k < D; k++) {
        // sX[rowLocal][k]: same address across the 64-lane group -> LDS broadcast.
        // sWr[k][col]: 64 lanes over 32 banks = 2-way alias, free on gfx950.
        acc = fmaf(sX[rowLocal][k], sWr[k][col], acc);
        acc = fmaf(sA[rowLocal][k], sWn[k][col], acc);
    }
    if (RELU) acc = fmaxf(acc, 0.0f);
    out[(long long)row * D + col] = acc;
}

extern "C" void kernel_launch(void* const* d_in, const int* in_sizes, int n_in,
                              void* d_out, int out_size, void* d_ws, size_t ws_size,
                              hipStream_t stream) {
    const float* x   = (const float*)d_in[0];
    const int*   edg = (const int*)d_in[1];
    const float* W1r = (const float*)d_in[2];
    const float* W1n = (const float*)d_in[3];
    const float* b1  = (const float*)d_in[4];
    const float* W2r = (const float*)d_in[5];
    const float* W2n = (const float*)d_in[6];
    const float* b2  = (const float*)d_in[7];
    float* out = (float*)d_out;

    const int* src = edg;              // edge_index[0]
    const int* dst = edg + N_EDGES;    // edge_index[1]

    float* agg = (float*)d_ws;                     // N*D
    float* h   = agg + (size_t)N_NODES * D;        // N*D
    size_t aggBytes = (size_t)N_NODES * D * sizeof(float);

    int sgrid = (int)(((long long)N_EDGES * 64 + 255) / 256);  // 200000 blocks

    // Layer 1
    hipMemsetAsync(agg, 0, aggBytes, stream);
    scatter_add<<<sgrid, 256, 0, stream>>>(x, src, dst, agg);
    dual_gemm<1><<<N_NODES / 4, 256, 0, stream>>>(x, agg, W1r, W1n, b1, h);

    // Layer 2
    hipMemsetAsync(agg, 0, aggBytes, stream);
    scatter_add<<<sgrid, 256, 0, stream>>>(h, src, dst, agg);
    dual_gemm<0><<<N_NODES / 4, 256, 0, stream>>>(h, agg, W2r, W2n, b2, out);
}

// Round 2
// 451.201 us; speedup vs baseline: 1.1668x; 1.1668x over previous
//
#include <hip/hip_runtime.h>

#define N_NODES 50000
#define N_EDGES 800000
#define D 64

// ---------------- CSR build (per call; ws is re-poisoned every launch) ------

__global__ void __launch_bounds__(256) hist_kernel(
    const int* __restrict__ dst, int* __restrict__ deg) {
    int e = blockIdx.x * blockDim.x + threadIdx.x;
    if (e < N_EDGES) atomicAdd(&deg[dst[e]], 1);
}

// Single-block exclusive scan of deg[0..N) -> startA (row start) and cursor.
__global__ void __launch_bounds__(1024) scan_kernel(
    const int* __restrict__ deg, int* __restrict__ startA, int* __restrict__ cursor) {
    const int T = 1024;
    const int CHUNK = (N_NODES + T - 1) / T;   // 49
    __shared__ int s[T];
    int t = threadIdx.x;
    int lo = t * CHUNK;
    int hi = min(lo + CHUNK, N_NODES);
    int p = 0;
    for (int i = lo; i < hi; i++) p += deg[i];
    s[t] = p;
    __syncthreads();
    // Hillis-Steele inclusive scan over 1024 partials
    for (int d = 1; d < T; d <<= 1) {
        int v = (t >= d) ? s[t - d] : 0;
        __syncthreads();
        s[t] += v;
        __syncthreads();
    }
    int off = s[t] - p;   // exclusive prefix for this chunk
    for (int i = lo; i < hi; i++) {
        startA[i] = off;
        cursor[i] = off;
        off += deg[i];
    }
}

__global__ void __launch_bounds__(256) fill_kernel(
    const int* __restrict__ src, const int* __restrict__ dst,
    int* __restrict__ cursor, int* __restrict__ csr) {
    int e = blockIdx.x * blockDim.x + threadIdx.x;
    if (e < N_EDGES) {
        int pos = atomicAdd(&cursor[dst[e]], 1);
        csr[pos] = src[e];
    }
}
// After fill: cursor[i] == row end for node i.

// ---------------- Fused per-layer kernel ------------------------------------
// out[i] = act( b + X[i] @ Wr + (sum_{j in in(i)} X[j]) @ Wn )
// Block = 1024 threads = 16 waves; one wave per node; 3125 blocks (50000/16).
template<int RELU>
__global__ void __launch_bounds__(1024) layer_kernel(
    const float* __restrict__ X,
    const int* __restrict__ rowStart, const int* __restrict__ rowEnd,
    const int* __restrict__ csr,
    const float* __restrict__ Wr, const float* __restrict__ Wn,
    const float* __restrict__ bias, float* __restrict__ out) {
    __shared__ float sWr[D][D];     // 16 KB
    __shared__ float sWn[D][D];     // 16 KB
    __shared__ float sRow[16][D];   // 4 KB  (X row per wave)
    __shared__ float sAgg[16][D];   // 4 KB  (aggregate row per wave)

    int tid  = threadIdx.x;
    int wave = tid >> 6;
    int lane = tid & 63;

    // Stage both 64x64 weight matrices: 4096 floats = 1024 float4 each.
    ((float4*)&sWr[0][0])[tid] = ((const float4*)Wr)[tid];
    ((float4*)&sWn[0][0])[tid] = ((const float4*)Wn)[tid];

    int node = blockIdx.x * 16 + wave;
    sRow[wave][lane] = X[(long long)node * D + lane];

    // Gather-sum incoming neighbor rows (coalesced 256B per edge, no atomics).
    float acc = 0.0f;
    int j  = rowStart[node];
    int je = rowEnd[node];
    for (; j + 3 < je; j += 4) {
        int s0 = csr[j], s1 = csr[j + 1], s2 = csr[j + 2], s3 = csr[j + 3];
        float v0 = X[(long long)s0 * D + lane];
        float v1 = X[(long long)s1 * D + lane];
        float v2 = X[(long long)s2 * D + lane];
        float v3 = X[(long long)s3 * D + lane];
        acc += v0 + v1 + v2 + v3;
    }
    for (; j < je; ++j) {
        int s = csr[j];
        acc += X[(long long)s * D + lane];
    }
    sAgg[wave][lane] = acc;
    __syncthreads();

    float o = bias[lane];
#pragma unroll
    for (int k = 0; k < D; k++) {
        // sRow/sAgg[wave][k]: wave-uniform address -> LDS broadcast.
        // sWr/sWn[k][lane]: 64 lanes over 32 banks = 2-way alias (free).
        o = fmaf(sRow[wave][k], sWr[k][lane], o);
        o = fmaf(sAgg[wave][k], sWn[k][lane], o);
    }
    if (RELU) o = fmaxf(o, 0.0f);
    out[(long long)node * D + lane] = o;
}

// ---------------- launch ----------------------------------------------------

extern "C" void kernel_launch(void* const* d_in, const int* in_sizes, int n_in,
                              void* d_out, int out_size, void* d_ws, size_t ws_size,
                              hipStream_t stream) {
    const float* x   = (const float*)d_in[0];
    const int*   edg = (const int*)d_in[1];
    const float* W1r = (const float*)d_in[2];
    const float* W1n = (const float*)d_in[3];
    const float* b1  = (const float*)d_in[4];
    const float* W2r = (const float*)d_in[5];
    const float* W2n = (const float*)d_in[6];
    const float* b2  = (const float*)d_in[7];
    float* out = (float*)d_out;

    const int* src = edg;              // edge_index[0]
    const int* dst = edg + N_EDGES;    // edge_index[1]

    // Workspace layout (16.6 MB total)
    int*   deg    = (int*)d_ws;
    int*   startA = deg + N_NODES;
    int*   cursor = startA + N_NODES;
    int*   csr    = cursor + N_NODES;
    float* h      = (float*)(csr + N_EDGES);

    const int EB = (N_EDGES + 255) / 256;   // 3125

    // CSR build (int atomics only)
    hipMemsetAsync(deg, 0, N_NODES * sizeof(int), stream);
    hist_kernel<<<EB, 256, 0, stream>>>(dst, deg);
    scan_kernel<<<1, 1024, 0, stream>>>(deg, startA, cursor);
    fill_kernel<<<EB, 256, 0, stream>>>(src, dst, cursor, csr);
    // now cursor[i] == row end

    const int LB = N_NODES / 16;            // 3125 blocks, 16 nodes each

    layer_kernel<1><<<LB, 1024, 0, stream>>>(x, startA, cursor, csr,
                                             W1r, W1n, b1, h);
    layer_kernel<0><<<LB, 1024, 0, stream>>>(h, startA, cursor, csr,
                                             W2r, W2n, b2, out);
}

// Round 3
// 293.016 us; speedup vs baseline: 1.7967x; 1.5399x over previous
//
#include <hip/hip_runtime.h>

#define N_NODES 50000
#define N_EDGES 800000
#define D 64

// ---------------- CSR build: hist -> wave-scan atomic alloc -> fill ---------

__global__ void __launch_bounds__(256) hist_kernel(
    const int* __restrict__ dst, int* __restrict__ deg) {
    int e = blockIdx.x * blockDim.x + threadIdx.x;
    if (e < N_EDGES) atomicAdd(&deg[dst[e]], 1);
}

// Rows need not be in node order -- just disjoint contiguous ranges.
// Wave-level inclusive scan of deg, one global atomicAdd per wave.
__global__ void __launch_bounds__(256) alloc_kernel(
    const int* __restrict__ deg, int* __restrict__ startA,
    int* __restrict__ cursor, int* __restrict__ total) {
    int i = blockIdx.x * blockDim.x + threadIdx.x;
    int lane = threadIdx.x & 63;
    int d = (i < N_NODES) ? deg[i] : 0;
    int incl = d;
#pragma unroll
    for (int off = 1; off < 64; off <<= 1) {
        int v = __shfl_up(incl, off, 64);
        if (lane >= off) incl += v;
    }
    int waveTot = __shfl(incl, 63, 64);
    int base = 0;
    if (lane == 63) base = atomicAdd(total, waveTot);
    base = __shfl(base, 63, 64);
    if (i < N_NODES) {
        int s = base + incl - d;
        startA[i] = s;
        cursor[i] = s;
    }
}

__global__ void __launch_bounds__(256) fill_kernel(
    const int* __restrict__ src, const int* __restrict__ dst,
    int* __restrict__ cursor, int* __restrict__ csr) {
    int e = blockIdx.x * blockDim.x + threadIdx.x;
    if (e < N_EDGES) {
        int pos = atomicAdd(&cursor[dst[e]], 1);
        csr[pos] = src[e];
    }
}
// After fill: cursor[i] == row end.

// ---------------- Gather: agg[i] = sum_{j in in(i)} X[j] -------------------
// One wave per node; 4 edges per iteration (lane = 16 feature-quads x 4 edges).
__global__ void __launch_bounds__(256) gather_kernel(
    const float* __restrict__ X, const int* __restrict__ startA,
    const int* __restrict__ rowEnd, const int* __restrict__ csr,
    float* __restrict__ agg) {
    int tid = threadIdx.x;
    int wave = tid >> 6, lane = tid & 63;
    int node = blockIdx.x * 4 + wave;
    int sub = lane >> 4, fq = lane & 15;
    const float4* X4 = (const float4*)X;
    int j = startA[node], je = rowEnd[node];
    float4 acc = make_float4(0.f, 0.f, 0.f, 0.f);
    for (; j + 4 <= je; j += 4) {
        int idx = csr[j + sub];
        float4 v = X4[idx * 16 + fq];
        acc.x += v.x; acc.y += v.y; acc.z += v.z; acc.w += v.w;
    }
    if (j + sub < je) {
        int idx = csr[j + sub];
        float4 v = X4[idx * 16 + fq];
        acc.x += v.x; acc.y += v.y; acc.z += v.z; acc.w += v.w;
    }
#pragma unroll
    for (int m = 16; m <= 32; m <<= 1) {
        acc.x += __shfl_xor(acc.x, m, 64);
        acc.y += __shfl_xor(acc.y, m, 64);
        acc.z += __shfl_xor(acc.z, m, 64);
        acc.w += __shfl_xor(acc.w, m, 64);
    }
    if (sub == 0) ((float4*)agg)[node * 16 + fq] = acc;
}

// ---------------- Register-blocked dual GEMM --------------------------------
// out[n] = act(b + X[n]@Wr + A[n]@Wn). Tile 64 nodes x 64 cols per block;
// each of 256 threads owns 4x4 outputs; all inner-loop LDS reads are b128.
template<int RELU>
__global__ void __launch_bounds__(256) dual_gemm(
    const float* __restrict__ X, const float* __restrict__ A,
    const float* __restrict__ Wr, const float* __restrict__ Wn,
    const float* __restrict__ bias, float* __restrict__ out) {
    __shared__ float sXT[D][D];   // [k][node] transposed
    __shared__ float sAT[D][D];
    __shared__ float sWr[D][D];   // [k][col]
    __shared__ float sWn[D][D];

    int tid = threadIdx.x;
    int node0 = blockIdx.x * 64;

#pragma unroll
    for (int i = 0; i < 4; i++) {
        int idx = tid + 256 * i;
        ((float4*)sWr)[idx] = ((const float4*)Wr)[idx];
        ((float4*)sWn)[idx] = ((const float4*)Wn)[idx];
    }
    const float4* X4 = (const float4*)X;
    const float4* A4 = (const float4*)A;
    int nd = tid & 63;
    int gn = min(node0 + nd, N_NODES - 1);
#pragma unroll
    for (int pass = 0; pass < 4; pass++) {
        int kq = (tid >> 6) + pass * 4;       // 0..15
        float4 v = X4[gn * 16 + kq];
        float4 w = A4[gn * 16 + kq];
        // writes: bank = nd%32 over 64 lanes -> 2-way alias (free)
        sXT[kq * 4 + 0][nd] = v.x; sXT[kq * 4 + 1][nd] = v.y;
        sXT[kq * 4 + 2][nd] = v.z; sXT[kq * 4 + 3][nd] = v.w;
        sAT[kq * 4 + 0][nd] = w.x; sAT[kq * 4 + 1][nd] = w.y;
        sAT[kq * 4 + 2][nd] = w.z; sAT[kq * 4 + 3][nd] = w.w;
    }
    __syncthreads();

    int nq = tid >> 4;    // node quad 0..15
    int cq = tid & 15;    // col  quad 0..15
    float4 b4 = ((const float4*)bias)[cq];
    float acc[4][4];
#pragma unroll
    for (int i = 0; i < 4; i++) {
        acc[i][0] = b4.x; acc[i][1] = b4.y; acc[i][2] = b4.z; acc[i][3] = b4.w;
    }

#pragma unroll 16
    for (int k = 0; k < D; k++) {
        float4 xv = *(const float4*)&sXT[k][nq * 4];
        float4 av = *(const float4*)&sAT[k][nq * 4];
        float4 wr = *(const float4*)&sWr[k][cq * 4];
        float4 wn = *(const float4*)&sWn[k][cq * 4];
        float xs[4] = {xv.x, xv.y, xv.z, xv.w};
        float as[4] = {av.x, av.y, av.z, av.w};
        float rs[4] = {wr.x, wr.y, wr.z, wr.w};
        float ns[4] = {wn.x, wn.y, wn.z, wn.w};
#pragma unroll
        for (int i = 0; i < 4; i++)
#pragma unroll
            for (int jj = 0; jj < 4; jj++) {
                acc[i][jj] = fmaf(xs[i], rs[jj], acc[i][jj]);
                acc[i][jj] = fmaf(as[i], ns[jj], acc[i][jj]);
            }
    }

    float4* out4 = (float4*)out;
#pragma unroll
    for (int i = 0; i < 4; i++) {
        int node = node0 + nq * 4 + i;
        if (node < N_NODES) {
            float4 r;
            r.x = acc[i][0]; r.y = acc[i][1]; r.z = acc[i][2]; r.w = acc[i][3];
            if (RELU) {
                r.x = fmaxf(r.x, 0.f); r.y = fmaxf(r.y, 0.f);
                r.z = fmaxf(r.z, 0.f); r.w = fmaxf(r.w, 0.f);
            }
            out4[node * 16 + cq] = r;
        }
    }
}

// ---------------- launch ----------------------------------------------------

extern "C" void kernel_launch(void* const* d_in, const int* in_sizes, int n_in,
                              void* d_out, int out_size, void* d_ws, size_t ws_size,
                              hipStream_t stream) {
    const float* x   = (const float*)d_in[0];
    const int*   edg = (const int*)d_in[1];
    const float* W1r = (const float*)d_in[2];
    const float* W1n = (const float*)d_in[3];
    const float* b1  = (const float*)d_in[4];
    const float* W2r = (const float*)d_in[5];
    const float* W2n = (const float*)d_in[6];
    const float* b2  = (const float*)d_in[7];
    float* out = (float*)d_out;

    const int* src = edg;              // edge_index[0]
    const int* dst = edg + N_EDGES;    // edge_index[1]

    // Workspace: deg[N] | total[16] | startA[N] | cursor[N] | csr[E] | agg[N*D]
    // = 16.6 MB (h lives in d_out).
    int*   deg    = (int*)d_ws;
    int*   total  = deg + N_NODES;
    int*   startA = deg + N_NODES + 16;
    int*   cursor = startA + N_NODES;
    int*   csr    = cursor + N_NODES;
    float* agg    = (float*)(csr + N_EDGES);
    float* h      = out;               // staged through d_out

    const int EB = (N_EDGES + 255) / 256;   // 3125
    const int NB = (N_NODES + 255) / 256;   // 196
    const int GB = N_NODES / 4;             // 12500
    const int MB = (N_NODES + 63) / 64;     // 782

    hipMemsetAsync(deg, 0, (N_NODES + 16) * sizeof(int), stream);
    hist_kernel<<<EB, 256, 0, stream>>>(dst, deg);
    alloc_kernel<<<NB, 256, 0, stream>>>(deg, startA, cursor, total);
    fill_kernel<<<EB, 256, 0, stream>>>(src, dst, cursor, csr);

    // Layer 1
    gather_kernel<<<GB, 256, 0, stream>>>(x, startA, cursor, csr, agg);
    dual_gemm<1><<<MB, 256, 0, stream>>>(x, agg, W1r, W1n, b1, h);
    // Layer 2 (gather fully precedes gemm2's in-place row writes)
    gather_kernel<<<GB, 256, 0, stream>>>(h, startA, cursor, csr, agg);
    dual_gemm<0><<<MB, 256, 0, stream>>>(h, agg, W2r, W2n, b2, out);
}

// Round 6
// 228.604 us; speedup vs baseline: 2.3029x; 1.2818x over previous
//
#include <hip/hip_runtime.h>

#define N_NODES 50000
#define N_EDGES 800000
#define D 64
#define NBUCKETS 196          // dst>>8, 0..195
#define CBLOCKS 256           // chunked edge blocks
#define CHUNK (N_EDGES / CBLOCKS)   // 3125

// ---------- Pass 1: per-bucket counts via LDS histograms --------------------
__global__ void __launch_bounds__(256) count_kernel(
    const int* __restrict__ dst, int* __restrict__ bucketCnt) {
    __shared__ int hist[256];
    int t = threadIdx.x;
    hist[t] = 0;
    __syncthreads();
    int lo = blockIdx.x * CHUNK, hi = lo + CHUNK;
    for (int i = lo + t; i < hi; i += 256)
        atomicAdd(&hist[dst[i] >> 8], 1);
    __syncthreads();
    if (hist[t] > 0) atomicAdd(&bucketCnt[t], hist[t]);
}

// ---------- Pass 2: scan 256 bucket counts -> base + padded cursors ---------
__global__ void __launch_bounds__(256) scan_kernel(
    const int* __restrict__ bucketCnt, int* __restrict__ bucketBase,
    int* __restrict__ cursorPad) {
    __shared__ int s[256];
    int t = threadIdx.x;
    int v = bucketCnt[t];
    s[t] = v;
    __syncthreads();
#pragma unroll
    for (int d = 1; d < 256; d <<= 1) {
        int u = (t >= d) ? s[t - d] : 0;
        __syncthreads();
        s[t] += u;
        __syncthreads();
    }
    int excl = s[t] - v;
    bucketBase[t] = excl;
    cursorPad[t * 16] = excl;
    if (t == 255) bucketBase[256] = s[255];
}

// ---------- Pass 3: scatter packed (src<<8 | dst&255) into bucket regions ---
__global__ void __launch_bounds__(256) scatter_kernel(
    const int* __restrict__ src, const int* __restrict__ dst,
    int* __restrict__ cursorPad, int* __restrict__ staged) {
    __shared__ int hist[256];
    __shared__ int curs[256];
    int t = threadIdx.x;
    hist[t] = 0;
    __syncthreads();
    int lo = blockIdx.x * CHUNK, hi = lo + CHUNK;
    for (int i = lo + t; i < hi; i += 256)
        atomicAdd(&hist[dst[i] >> 8], 1);
    __syncthreads();
    if (hist[t] > 0) curs[t] = atomicAdd(&cursorPad[t * 16], hist[t]);
    __syncthreads();
    for (int i = lo + t; i < hi; i += 256) {
        int d = dst[i];
        int b = d >> 8;
        int pos = atomicAdd(&curs[b], 1);
        staged[pos] = (src[i] << 8) | (d & 255);
    }
}

// ---------- Pass 4: per-bucket CSR build (LDS counters, localized writes) ---
__global__ void __launch_bounds__(256) csr_build_kernel(
    const int* __restrict__ bucketBase, const int* __restrict__ staged,
    int* __restrict__ csr, int* __restrict__ startA, int* __restrict__ endA) {
    __shared__ int deg[256];
    __shared__ int sc[256];
    __shared__ int curs[256];
    int k = blockIdx.x;
    int t = threadIdx.x;
    int base = bucketBase[k];
    int cnt  = bucketBase[k + 1] - base;
    deg[t] = 0;
    __syncthreads();
    for (int i = t; i < cnt; i += 256)
        atomicAdd(&deg[staged[base + i] & 255], 1);
    __syncthreads();
    int v = deg[t];
    sc[t] = v;
    __syncthreads();
#pragma unroll
    for (int d = 1; d < 256; d <<= 1) {
        int u = (t >= d) ? sc[t - d] : 0;
        __syncthreads();
        sc[t] += u;
        __syncthreads();
    }
    int start = sc[t] - v;
    int node = k * 256 + t;
    if (node < N_NODES) {
        startA[node] = base + start;
        endA[node]   = base + start + v;
    }
    curs[t] = start;
    __syncthreads();
    for (int i = t; i < cnt; i += 256) {
        int e = staged[base + i];
        int pos = atomicAdd(&curs[e & 255], 1);
        csr[base + pos] = e >> 8;
    }
}

// ---------- Gather: agg[n] = sum_{j in in(n)} X[j] --------------------------
// One wave per node. Batch-load 64 csr indices coalesced, shfl-distribute.
// ALL __shfl calls are exec-uniform (whole wave executes them; divergence is
// confined to the predicated load/add) -- shfl from an inactive source lane
// is undefined on CDNA and was the R4/R5 correctness bug.
__global__ void __launch_bounds__(256) gather_kernel(
    const float* __restrict__ X, const int* __restrict__ startA,
    const int* __restrict__ endA, const int* __restrict__ csr,
    float* __restrict__ agg) {
    int tid = threadIdx.x;
    int wave = tid >> 6, lane = tid & 63;
    int node = blockIdx.x * 4 + wave;
    int sub = lane >> 4, fq = lane & 15;
    const float4* X4 = (const float4*)X;
    int j0 = startA[node], je = endA[node];
    float4 acc = make_float4(0.f, 0.f, 0.f, 0.f);
    for (int jb = j0; jb < je; jb += 64) {   // je wave-uniform
        int idx = jb + lane;
        int p = csr[idx < je ? idx : (je - 1)];
        int m = min(64, je - jb);            // wave-uniform
        int b = 0;
        for (; b + 8 <= m; b += 8) {         // uniform condition, no divergence
            int i0 = __shfl(p, b + sub, 64);
            int i1 = __shfl(p, b + 4 + sub, 64);
            float4 v0 = X4[i0 * 16 + fq];
            float4 v1 = X4[i1 * 16 + fq];
            acc.x += v0.x; acc.y += v0.y; acc.z += v0.z; acc.w += v0.w;
            acc.x += v1.x; acc.y += v1.y; acc.z += v1.z; acc.w += v1.w;
        }
        for (; b < m; b += 4) {              // uniform condition
            int sidx = b + sub;
            int sclamp = sidx < m ? sidx : (m - 1);   // valid, active source
            int i0 = __shfl(p, sclamp, 64);  // executed by ALL lanes
            if (sidx < m) {                  // divergence only around the add
                float4 v = X4[i0 * 16 + fq];
                acc.x += v.x; acc.y += v.y; acc.z += v.z; acc.w += v.w;
            }
        }
    }
#pragma unroll
    for (int mk = 16; mk <= 32; mk <<= 1) {
        acc.x += __shfl_xor(acc.x, mk, 64);
        acc.y += __shfl_xor(acc.y, mk, 64);
        acc.z += __shfl_xor(acc.z, mk, 64);
        acc.w += __shfl_xor(acc.w, mk, 64);
    }
    if (sub == 0) ((float4*)agg)[node * 16 + fq] = acc;
}

// ---------- Register-blocked dual GEMM --------------------------------------
template<int RELU>
__global__ void __launch_bounds__(256) dual_gemm(
    const float* __restrict__ X, const float* __restrict__ A,
    const float* __restrict__ Wr, const float* __restrict__ Wn,
    const float* __restrict__ bias, float* __restrict__ out) {
    __shared__ float sXT[D][D];
    __shared__ float sAT[D][D];
    __shared__ float sWr[D][D];
    __shared__ float sWn[D][D];

    int tid = threadIdx.x;
    int node0 = blockIdx.x * 64;

#pragma unroll
    for (int i = 0; i < 4; i++) {
        int idx = tid + 256 * i;
        ((float4*)sWr)[idx] = ((const float4*)Wr)[idx];
        ((float4*)sWn)[idx] = ((const float4*)Wn)[idx];
    }
    const float4* X4 = (const float4*)X;
    const float4* A4 = (const float4*)A;
    int nd = tid & 63;
    int gn = min(node0 + nd, N_NODES - 1);
#pragma unroll
    for (int pass = 0; pass < 4; pass++) {
        int kq = (tid >> 6) + pass * 4;
        float4 v = X4[gn * 16 + kq];
        float4 w = A4[gn * 16 + kq];
        sXT[kq * 4 + 0][nd] = v.x; sXT[kq * 4 + 1][nd] = v.y;
        sXT[kq * 4 + 2][nd] = v.z; sXT[kq * 4 + 3][nd] = v.w;
        sAT[kq * 4 + 0][nd] = w.x; sAT[kq * 4 + 1][nd] = w.y;
        sAT[kq * 4 + 2][nd] = w.z; sAT[kq * 4 + 3][nd] = w.w;
    }
    __syncthreads();

    int nq = tid >> 4;
    int cq = tid & 15;
    float4 b4 = ((const float4*)bias)[cq];
    float acc[4][4];
#pragma unroll
    for (int i = 0; i < 4; i++) {
        acc[i][0] = b4.x; acc[i][1] = b4.y; acc[i][2] = b4.z; acc[i][3] = b4.w;
    }

#pragma unroll 16
    for (int k = 0; k < D; k++) {
        float4 xv = *(const float4*)&sXT[k][nq * 4];
        float4 av = *(const float4*)&sAT[k][nq * 4];
        float4 wr = *(const float4*)&sWr[k][cq * 4];
        float4 wn = *(const float4*)&sWn[k][cq * 4];
        float xs[4] = {xv.x, xv.y, xv.z, xv.w};
        float as[4] = {av.x, av.y, av.z, av.w};
        float rs[4] = {wr.x, wr.y, wr.z, wr.w};
        float ns[4] = {wn.x, wn.y, wn.z, wn.w};
#pragma unroll
        for (int i = 0; i < 4; i++)
#pragma unroll
            for (int jj = 0; jj < 4; jj++) {
                acc[i][jj] = fmaf(xs[i], rs[jj], acc[i][jj]);
                acc[i][jj] = fmaf(as[i], ns[jj], acc[i][jj]);
            }
    }

    float4* out4 = (float4*)out;
#pragma unroll
    for (int i = 0; i < 4; i++) {
        int node = node0 + nq * 4 + i;
        if (node < N_NODES) {
            float4 r;
            r.x = acc[i][0]; r.y = acc[i][1]; r.z = acc[i][2]; r.w = acc[i][3];
            if (RELU) {
                r.x = fmaxf(r.x, 0.f); r.y = fmaxf(r.y, 0.f);
                r.z = fmaxf(r.z, 0.f); r.w = fmaxf(r.w, 0.f);
            }
            out4[node * 16 + cq] = r;
        }
    }
}

// ---------- launch ----------------------------------------------------------
extern "C" void kernel_launch(void* const* d_in, const int* in_sizes, int n_in,
                              void* d_out, int out_size, void* d_ws, size_t ws_size,
                              hipStream_t stream) {
    const float* x   = (const float*)d_in[0];
    const int*   edg = (const int*)d_in[1];
    const float* W1r = (const float*)d_in[2];
    const float* W1n = (const float*)d_in[3];
    const float* b1  = (const float*)d_in[4];
    const float* W2r = (const float*)d_in[5];
    const float* W2n = (const float*)d_in[6];
    const float* b2  = (const float*)d_in[7];
    float* out = (float*)d_out;

    const int* src = edg;
    const int* dst = edg + N_EDGES;

    // ws layout (16.42 MB):
    //   bucketCnt[256] | cursorPad[4096] | bucketBase[260] |
    //   csr[E] | startA[N] | endA[N] | UNION{ staged[E] , agg[N*D] }
    // staged is dead after csr_build; agg first written by gather (after it).
    int* bucketCnt  = (int*)d_ws;
    int* cursorPad  = bucketCnt + 256;
    int* bucketBase = cursorPad + 4096;
    int* csr        = bucketBase + 260;
    int* startA     = csr + N_EDGES;
    int* endA       = startA + N_NODES;
    int* staged     = endA + N_NODES;          // E ints  (3.2 MB)
    float* agg      = (float*)staged;          // N*D floats (12.8 MB), aliases
    float* h        = out;   // layer-1 activations staged through d_out

    hipMemsetAsync(bucketCnt, 0, 256 * sizeof(int), stream);
    count_kernel<<<CBLOCKS, 256, 0, stream>>>(dst, bucketCnt);
    scan_kernel<<<1, 256, 0, stream>>>(bucketCnt, bucketBase, cursorPad);
    scatter_kernel<<<CBLOCKS, 256, 0, stream>>>(src, dst, cursorPad, staged);
    csr_build_kernel<<<NBUCKETS, 256, 0, stream>>>(bucketBase, staged, csr,
                                                   startA, endA);

    const int GB = N_NODES / 4;          // 12500
    const int MB = (N_NODES + 63) / 64;  // 782

    gather_kernel<<<GB, 256, 0, stream>>>(x, startA, endA, csr, agg);
    dual_gemm<1><<<MB, 256, 0, stream>>>(x, agg, W1r, W1n, b1, h);
    gather_kernel<<<GB, 256, 0, stream>>>(h, startA, endA, csr, agg);
    dual_gemm<0><<<MB, 256, 0, stream>>>(h, agg, W2r, W2n, b2, out);
}